// Round 8
// baseline (4306.580 us; speedup 1.0000x reference)
//
#include <hip/hip_runtime.h>
#include <stdint.h>

typedef unsigned long long ull;

#define QCAP 256u   // per-wave LDS ring entries (power of 2)

static __device__ __forceinline__ ull packkey(float f, int v) {
    uint32_t u = __float_as_uint(f);
    u = (u & 0x80000000u) ? ~u : (u | 0x80000000u);
    return ((ull)u << 32) | (ull)(~(uint32_t)v);
}
static __device__ __forceinline__ int aload(const int* p) {
    return __hip_atomic_load(p, __ATOMIC_RELAXED, __HIP_MEMORY_SCOPE_AGENT);
}
static __device__ __forceinline__ ull aloadu(const ull* p) {
    return __hip_atomic_load(p, __ATOMIC_RELAXED, __HIP_MEMORY_SCOPE_AGENT);
}

// ---------------- build in-degree of "absorption" DAG ----------------
__global__ void k_build4(const int* __restrict__ neighs, const float* __restrict__ hier,
                         int* __restrict__ pred, long E4, int K) {
    long t = (long)blockIdx.x * blockDim.x + threadIdx.x;
    if (t >= E4) return;
    long e = t * 4;
    int u = (int)(e / K);
    ull ku = packkey(hier[u], u);
    int4 w4 = *(const int4*)(neighs + e);
    int ws[4] = {w4.x, w4.y, w4.z, w4.w};
    #pragma unroll
    for (int j = 0; j < 4; j++) {
        int w = ws[j];
        if (w < 0) continue;
        if (ku > packkey(hier[w], w))
            __hip_atomic_fetch_add(&pred[w], 1, __ATOMIC_RELAXED, __HIP_MEMORY_SCOPE_AGENT);
    }
}
__global__ void k_build1(const int* __restrict__ neighs, const float* __restrict__ hier,
                         int* __restrict__ pred, long E, int K) {
    long e = (long)blockIdx.x * blockDim.x + threadIdx.x;
    if (e >= E) return;
    int w = neighs[e];
    if (w < 0) return;
    int u = (int)(e / K);
    if (packkey(hier[u], u) > packkey(hier[w], w))
        __hip_atomic_fetch_add(&pred[w], 1, __ATOMIC_RELAXED, __HIP_MEMORY_SCOPE_AGENT);
}

// ---------------- process one decided vertex, wave-wide; claim+queue children ----------------
static __device__ __forceinline__ void process_v(
    int v, bool cen, int lane,
    const int* __restrict__ neighs, const float* __restrict__ hier,
    ull* __restrict__ best, int* __restrict__ pred, int* __restrict__ status,
    int K, unsigned* __restrict__ myq, unsigned& head, unsigned& tail)
{
    ull kv = packkey(hier[v], v);
    const int* row = neighs + (size_t)v * (size_t)K;
    for (int k0 = 0; k0 < K; k0 += 64) {
        int k = k0 + lane;
        int w = (k < K) ? row[k] : -1;
        bool lower = false;
        if (w >= 0) lower = kv > packkey(hier[w], w);

        bool childAbs = false, childCen = false;
        if (cen) {
            ull oldb = ~0ull;
            if (lower)
                oldb = __hip_atomic_fetch_max(&best[w], kv,
                                              __ATOMIC_RELAXED, __HIP_MEMORY_SCOPE_AGENT);
            childAbs = lower && (oldb == 0ull);   // we are the unique first absorber of w
            __threadfence();                      // our maxes land before our subs
        }
        int oldp = 0;
        if (lower)
            oldp = __hip_atomic_fetch_add(&pred[w], -1,
                                          __ATOMIC_RELAXED, __HIP_MEMORY_SCOPE_AGENT);
        bool lastp = lower && (oldp == 1);        // we released w's last in-edge
        if (__any(lastp)) {
            __threadfence();                      // order the best-read after our sub
            if (lastp) {
                ull b = aloadu(&best[w]);         // final (all maxes at MALL before last sub)
                if (b == 0ull) childCen = true;   // unique center discovery
                // b!=0: absorbed; the old==0 max lane (somewhere) handles it
            }
        }
        bool want = childAbs || childCen;
        unsigned avail = QCAP - (tail - head);
        ull wm = __ballot(want);
        unsigned pre = (unsigned)__popcll(wm & ((1ull << lane) - 1ull));
        bool allowed = want && (pre < avail);     // queue-full => drop, owner backstop
        bool claimed = false;
        if (allowed) {
            int exp0 = 0;
            claimed = __hip_atomic_compare_exchange_strong(
                &status[w], &exp0, 1, __ATOMIC_RELAXED, __ATOMIC_RELAXED,
                __HIP_MEMORY_SCOPE_AGENT);
        }
        ull cm = __ballot(claimed);
        unsigned pos = (unsigned)__popcll(cm & ((1ull << lane) - 1ull));
        if (claimed)
            myq[(tail + pos) & (QCAP - 1u)] = (unsigned)w | (childCen ? 0x80000000u : 0u);
        tail += (unsigned)__popcll(cm);
    }
}

// ---------------- poll one owned 64-vertex group (seed discovery + backstop) ----------------
static __device__ __forceinline__ bool poll_group(
    int gb, bool pend, int lane,
    const int* __restrict__ neighs, const float* __restrict__ hier,
    ull* __restrict__ best, int* __restrict__ pred, int* __restrict__ status,
    int K, unsigned* __restrict__ myq, unsigned& head, unsigned& tail, bool& found)
{
    if (!__any(pend)) return pend;
    int v = gb + lane;
    int st = 1;
    if (pend) st = aload(&status[v]);
    bool drop  = pend && (st != 0);        // claimed elsewhere -> handled
    bool check = pend && (st == 0);
    ull b = 0; int p = 1;
    if (check) {
        b = aloadu(&best[v]);
        p = aload(&pred[v]);
    }
    bool abs1 = check && (b != 0ull);
    bool cenm = check && (b == 0ull) && (p == 0);
    bool cen1 = false;
    if (__any(cenm)) {
        __threadfence();
        ull b2 = 0;
        if (cenm) b2 = aloadu(&best[v]);
        cen1 = cenm && (b2 == 0ull);
        abs1 |= cenm && (b2 != 0ull);
    }
    bool want = abs1 || cen1;
    bool claimed = false;
    if (want) {
        int exp0 = 0;
        claimed = __hip_atomic_compare_exchange_strong(
            &status[v], &exp0, 1, __ATOMIC_RELAXED, __ATOMIC_RELAXED,
            __HIP_MEMORY_SCOPE_AGENT);
    }
    ull cm = __ballot(claimed);
    ull cenmask = __ballot(cen1);
    while (cm) {
        int l = __ffsll((unsigned long long)cm) - 1;
        cm &= cm - 1;
        process_v(gb + l, (cenmask >> l) & 1ull, lane,
                  neighs, hier, best, pred, status, K, myq, head, tail);
        found = true;
    }
    return pend && !drop && !want;   // want&&!claimed: another claimer handles it
}

// ---------------- propagate: wave-BFS fast path + owner-poll backstop ----------------
__global__ __launch_bounds__(256, 4)
void k_propagate(const int* __restrict__ neighs, const float* __restrict__ hier,
                 ull* __restrict__ best, int* __restrict__ pred, int* __restrict__ status,
                 int V, int K, int NW) {
    __shared__ unsigned q[4][QCAP];
    const int gtid = blockIdx.x * blockDim.x + threadIdx.x;
    const int wv = gtid >> 6, lane = gtid & 63;
    unsigned* myq = q[(threadIdx.x >> 6)];
    const int G = (V + 63) >> 6;
    int gb0 = (wv < G) ? (wv << 6) : -1;
    int g1 = wv + NW;
    int gb1 = (g1 < G) ? (g1 << 6) : -1;
    bool p0 = gb0 >= 0 && gb0 + lane < V;
    bool p1 = gb1 >= 0 && gb1 + lane < V;
    unsigned head = 0, tail = 0;   // wave-uniform ring indices
    long sweeps = 0;

    while (__any(p0 || p1) || head != tail) {
        bool found = false;
        while (head != tail) {                 // service our queue (chain fast path)
            unsigned ent = myq[head & (QCAP - 1u)];
            head++;
            process_v((int)(ent & 0x7FFFFFFFu), (ent >> 31) != 0, lane,
                      neighs, hier, best, pred, status, K, myq, head, tail);
            found = true;
        }
        p0 = poll_group(gb0, p0, lane, neighs, hier, best, pred, status, K, myq, head, tail, found);
        p1 = poll_group(gb1, p1, lane, neighs, hier, best, pred, status, K, myq, head, tail, found);
        if (!found) {
            __builtin_amdgcn_s_sleep(2);
            if (++sweeps > 300000L) break;     // safety net: never hang the bench
        }
    }
}

// ---------------- compact centers per segment ----------------
__global__ void k_compact(const float* __restrict__ hier,
                          const ull* __restrict__ best,
                          const int* __restrict__ row_splits,
                          ull* __restrict__ segKeys,
                          int* __restrict__ segIds,
                          int* __restrict__ counters,
                          int V, int NSEG) {
    int v = blockIdx.x * blockDim.x + threadIdx.x;
    if (v >= V) return;
    if (best[v] != 0ull) return;            // center <=> never absorbed
    int s = 0;
    while (s + 1 < NSEG && v >= row_splits[s + 1]) s++;
    int p = atomicAdd(&counters[s], 1);
    int base = row_splits[s];
    segKeys[base + p] = packkey(hier[v], v);
    segIds[base + p]  = v;
}

// ---------------- rs prefix (tiny) ----------------
__global__ void k_rs(const int* __restrict__ counters,
                     int* __restrict__ rsBase,
                     int* __restrict__ rs_out,
                     int NSEG) {
    if (blockIdx.x == 0 && threadIdx.x == 0) {
        int acc = 0;
        rs_out[0] = 0;
        for (int s = 0; s < NSEG; s++) {
            rsBase[s] = acc;
            acc += counters[s];
            rs_out[s + 1] = acc;
        }
    }
}

// ---------------- rank centers -> cid, sel ----------------
__global__ void k_rank(const ull* __restrict__ segKeys,
                       const int* __restrict__ segIds,
                       const int* __restrict__ counters,
                       const int* __restrict__ rsBase,
                       const int* __restrict__ row_splits,
                       int* __restrict__ cidOf,
                       int* __restrict__ sel_out,
                       int V, int NSEG) {
    int t = blockIdx.x * blockDim.x + threadIdx.x;
    if (t >= V) return;
    int s = 0;
    while (s + 1 < NSEG && t >= row_splits[s + 1]) s++;
    int base = row_splits[s];
    int j = t - base;
    int cnt = counters[s];
    if (j >= cnt) return;
    ull mk = segKeys[t];
    int r = 0;
    for (int i = 0; i < cnt; i++) r += (segKeys[base + i] > mk) ? 1 : 0;
    int cid = rsBase[s] + r;
    int v = segIds[t];
    cidOf[v] = cid;
    sel_out[cid] = v;
}

// ---------------- final cluster assignment ----------------
__global__ void k_assign(const ull* __restrict__ best,
                         const int* __restrict__ cidOf,
                         int* __restrict__ clus_out,
                         int V) {
    int v = blockIdx.x * blockDim.x + threadIdx.x;
    if (v >= V) return;
    ull b = best[v];
    int c;
    if (b == 0ull) {
        c = cidOf[v];                                   // center
    } else {
        uint32_t a = ~(uint32_t)(b & 0xFFFFFFFFull);    // absorber global index
        c = cidOf[a];
    }
    clus_out[v] = c;
}

extern "C" void kernel_launch(void* const* d_in, const int* in_sizes, int n_in,
                              void* d_out, int out_size, void* d_ws, size_t ws_size,
                              hipStream_t stream) {
    const int*   neighs     = (const int*)d_in[0];
    const float* hier       = (const float*)d_in[1];
    const int*   row_splits = (const int*)d_in[2];

    const int V    = in_sizes[1];
    const int K    = in_sizes[0] / V;
    const int NSEG = in_sizes[2] - 1;
    const long E   = (long)V * (long)K;

    int* out      = (int*)d_out;
    int* sel_out  = out;
    int* rs_out   = out + V;
    int* clus_out = out + V + NSEG + 1;

    // ws: [best 8V][pred 4V][status 4V][cnts 256B][segKeys 8V][segIds 4V][cidOf 4V] = 32V+256
    char* w = (char*)d_ws;
    ull* best    = (ull*)(w);
    int* pred    = (int*)(w + (size_t)8  * V);
    int* status  = (int*)(w + (size_t)12 * V);
    int* cnts    = (int*)(w + (size_t)16 * V);
    ull* segKeys = (ull*)(w + (size_t)16 * V + 256);
    int* segIds  = (int*)(w + (size_t)24 * V + 256);
    int* cidOf   = (int*)(w + (size_t)28 * V + 256);

    const int B  = 256;
    const int gV = (V + B - 1) / B;

    (void)hipMemsetAsync(w, 0, (size_t)16 * V + 256, stream);     // best, pred, status, cnts
    (void)hipMemsetAsync(sel_out, 0xFF, (size_t)4 * V, stream);   // sel padded with -1

    if ((K & 3) == 0) {
        long E4 = E / 4;
        k_build4<<<(int)((E4 + B - 1) / B), B, 0, stream>>>(neighs, hier, pred, E4, K);
    } else {
        k_build1<<<(int)((E + B - 1) / B), B, 0, stream>>>(neighs, hier, pred, E, K);
    }

    const int PB = 1024;                  // 4 blocks/CU guaranteed co-resident
    const int NW = PB * B / 64;           // 4096 waves; each owns <=2 groups of 64
    k_propagate<<<PB, B, 0, stream>>>(neighs, hier, best, pred, status, V, K, NW);

    k_compact<<<gV, B, 0, stream>>>(hier, best, row_splits, segKeys, segIds, cnts, V, NSEG);
    k_rs<<<1, 64, 0, stream>>>(cnts, cnts + 16, rs_out, NSEG);
    k_rank<<<gV, B, 0, stream>>>(segKeys, segIds, cnts, cnts + 16, row_splits,
                                 cidOf, sel_out, V, NSEG);
    k_assign<<<gV, B, 0, stream>>>(best, cidOf, clus_out, V);
}